// Round 7
// baseline (2222.372 us; speedup 1.0000x reference)
//
#include <hip/hip_runtime.h>
#include <hip/hip_bf16.h>

typedef __attribute__((ext_vector_type(8))) short  s8v;   // 8 x bf16 bits
typedef __attribute__((ext_vector_type(4))) float  f4v;
typedef __attribute__((ext_vector_type(2))) unsigned long long ull2;
typedef unsigned long long ull;

#define XH 256
#define XW 256
#define PLANE 65536
#define PCW 66          // padded tile width (64 + 2 halo)

__device__ __forceinline__ unsigned short f2bf(float f){
  __hip_bfloat16 h = __float2bfloat16(f);          // HW RNE cvt
  return __builtin_bit_cast(unsigned short, h);
}
__device__ __forceinline__ float bf2f(unsigned short h){
  unsigned int u = ((unsigned int)h) << 16;
  return __builtin_bit_cast(float, u);
}

// ---------------- K1: per-(b,c) plane mean ----------------
__global__ __launch_bounds__(256) void pool_k(const float* __restrict__ x,
                                              float* __restrict__ pooled){
  int plane = blockIdx.x, t = threadIdx.x;
  const f4v* p = (const f4v*)(x + (size_t)plane * PLANE);
  float s = 0.f;
  #pragma unroll 8
  for(int it = 0; it < 64; ++it){
    f4v v = p[t + (it << 8)];
    s += v[0] + v[1] + v[2] + v[3];
  }
  #pragma unroll
  for(int m = 32; m >= 1; m >>= 1) s += __shfl_xor(s, m);
  __shared__ float ps[4];
  if((t & 63) == 0) ps[t >> 6] = s;
  __syncthreads();
  if(t == 0) pooled[plane] = (ps[0] + ps[1] + ps[2] + ps[3]) * (1.f / 65536.f);
}

// ---------------- K2: direction MLP + BN-folded weight pack ----------------
// PK layout (bf16): byte = s*4096 + n*64 + g*16 + j*2 (s=K32-step, n=oc,
// g=lane>>4, j=0..7). k = 32s + 8g + j = tap*64 + c, tap = s>>1,
// c = 32*(s&1) + 8g + j.  Even s = channels 0-31 (pass0), odd s = 32-63.
__global__ __launch_bounds__(256) void prep_k(const float* __restrict__ convw,
    const float* __restrict__ convb, const float* __restrict__ gamma,
    const float* __restrict__ beta,  const float* __restrict__ mean,
    const float* __restrict__ var,   const float* __restrict__ d1w,
    const float* __restrict__ d1b,   const float* __restrict__ d2w,
    const float* __restrict__ d2b,   const float* __restrict__ pooled,
    float* __restrict__ dirv, float* __restrict__ bias2,
    unsigned short* __restrict__ pk, float* __restrict__ outdir){
  int blk = blockIdx.x, t = threadIdx.x;
  if(blk == 0){
    __shared__ float h1s[16][8];
    if(t < 128){                       // h1[b][o] over 128 lanes
      int b = t >> 3, o = t & 7;
      float a = d1b[o];
      #pragma unroll 8
      for(int c = 0; c < 64; ++c) a = fmaf(pooled[b * 64 + c], d1w[o * 64 + c], a);
      h1s[b][o] = fmaxf(a, 0.f);
    } else if(t >= 128 && t < 192){
      int oc = t - 128;
      float sc = gamma[oc] * rsqrtf(var[oc] + 1e-5f);
      bias2[oc] = (convb[oc] - mean[oc]) * sc + beta[oc];
    }
    __syncthreads();
    if(t < 16){
      float logit = d2b[0];
      #pragma unroll
      for(int o = 0; o < 8; ++o) logit = fmaf(h1s[t][o], d2w[o], logit);
      float dv = 1.f / (1.f + __expf(-logit));
      dirv[t] = dv;
      outdir[t] = dv;                  // direction output (tuple tail)
    }
  } else {
    int idx = ((blk - 1) << 8) + t;    // < 36864
    int j = idx & 7, g = (idx >> 3) & 3, n = (idx >> 5) & 63, s = idx >> 11;
    int c = ((s & 1) << 5) + (g << 3) + j, tap = s >> 1;
    float sc = gamma[n] * rsqrtf(var[n] + 1e-5f);
    pk[idx] = f2bf(convw[(n * 64 + c) * 9 + tap] * sc);
  }
}

// ---------------- K3: fused conv+BN+relu+attn+sigmoid+mul ----------------
// Block = 256 thr (4 waves), tile 4 rows x 64 cols.  TWO channel passes of 32
// ch each -> LDS 25.3KB+1KB -> 6 blocks/CU (24 waves).  LDS xs: [pix][32 ch]
// = 64B rows, 8B slots swizzled s8 = cgrp ^ ((pix>>2)&7).  Writes (chunk
// lane-minor) sweep all 8 slots; reads via 2x ds_read_b64 at (2lg+h)^pq hit
// all 32 banks (b64 floor).  Output phase re-reads fp32 x from global (f4v).
__global__ __launch_bounds__(256, 6) void main_k(const float* __restrict__ x,
    const float* __restrict__ attnw, const float* __restrict__ attnb,
    const float* __restrict__ dirv,  const float* __restrict__ bias2,
    const unsigned short* __restrict__ pk, float* __restrict__ out){
  __shared__ __align__(16) char lds[6 * PCW * 64];       // 25344 B
  __shared__ __align__(16) float att_s[256];

  const int bid = blockIdx.x;
  const int bs  = ((bid & 7) << 9) | (bid >> 3);     // XCD swizzle (4096%8==0)
  const int wblk = bs & 3, hblk = (bs >> 2) & 63, b = bs >> 8;
  const int w0 = wblk << 6, h0 = hblk << 2;
  const int t = threadIdx.x, lane = t & 63, wv = t >> 6;
  const int lm = lane & 15, lg = lane >> 4;
  const size_t bbase = (size_t)b * 64 * PLANE;

  const char* pkl = (const char*)pk + lm * 64 + (lg << 4);

#define BLOAD(BUF, S) { \
    _Pragma("unroll") \
    for(int jn = 0; jn < 4; ++jn) BUF[jn] = *(const s8v*)(pkl + ((S) << 12) + (jn << 10)); }

  // first 3 pass0 steps' weights fly under the staging
  s8v bb0[4], bb1[4], bb2[4];
  BLOAD(bb0, 0); BLOAD(bb1, 2); BLOAD(bb2, 4);

  // ---- stage 32 channels (pass P) of the 6x66 halo as bf16 [pix][32ch]
#define STAGE(P) { \
    _Pragma("unroll") \
    for(int it = 0; it < 4; ++it){ \
      int task = t + (it << 8); \
      if(task < 864){                      /* 18 chunk * 6 hh * 8 cgrp */ \
        int chunk = task % 18; int rem = task / 18; \
        int hh = rem % 6, cg = rem / 6; \
        int hhg = h0 - 1 + hh; \
        int wcg = w0 - 4 + (chunk << 2); \
        f4v v0 = {0,0,0,0}, v1 = {0,0,0,0}, v2 = {0,0,0,0}, v3 = {0,0,0,0}; \
        if(hhg >= 0 && hhg < XH && wcg >= 0 && wcg + 3 < XW){ \
          const float* bp = x + bbase + (size_t)(((((P) << 3) + cg)) << 2) * PLANE \
                              + (size_t)hhg * XW + wcg; \
          v0 = *(const f4v*)bp;             v1 = *(const f4v*)(bp + PLANE); \
          v2 = *(const f4v*)(bp + 2*PLANE); v3 = *(const f4v*)(bp + 3*PLANE); \
        } \
        _Pragma("unroll") \
        for(int e = 0; e < 4; ++e){ \
          int pc = (chunk << 2) - 3 + e; \
          if(pc >= 0 && pc < PCW){ \
            int pix = hh * PCW + pc; \
            int s8 = cg ^ ((pix >> 2) & 7); \
            ull d = (ull)f2bf(v0[e]) | ((ull)f2bf(v1[e]) << 16) \
                  | ((ull)f2bf(v2[e]) << 32) | ((ull)f2bf(v3[e]) << 48); \
            *(ull*)(lds + pix * 64 + (s8 << 3)) = d; \
          } } } } }

  f4v acc[4][4];
  #pragma unroll
  for(int i = 0; i < 4; ++i)
    #pragma unroll
    for(int j = 0; j < 4; ++j) acc[i][j] = (f4v){0.f, 0.f, 0.f, 0.f};

  const int pixb = (wv + 1) * PCW + lm + 1;

#define ALOAD(AFR, D) { \
    _Pragma("unroll") \
    for(int i = 0; i < 4; ++i){ \
      int pix = pixb + (i << 4) + (D); \
      int pq = (pix >> 2) & 7; \
      ull2 tv; \
      tv[0] = *(const ull*)(lds + pix * 64 + ((((lg << 1)    ) ^ pq) << 3)); \
      tv[1] = *(const ull*)(lds + pix * 64 + ((((lg << 1) | 1) ^ pq) << 3)); \
      AFR[i] = __builtin_bit_cast(s8v, tv); } }
#define MF(AFR, BUF) { \
    _Pragma("unroll") \
    for(int i = 0; i < 4; ++i){ _Pragma("unroll") for(int j = 0; j < 4; ++j) \
      acc[i][j] = __builtin_amdgcn_mfma_f32_16x16x32_bf16(AFR[i], BUF[j], acc[i][j], 0, 0, 0); } }
// step S (tap = S>>1), consume BUF, then refill BUF with step NS (-1 = none)
#define STEPP(S, BUF, NS) { \
    s8v afr[4]; \
    const int dd = ((((S) >> 1) / 3) - 1) * PCW + (((S) >> 1) % 3) - 1; \
    ALOAD(afr, dd); \
    __builtin_amdgcn_s_setprio(1); \
    MF(afr, BUF); \
    __builtin_amdgcn_s_setprio(0); \
    if((NS) >= 0) BLOAD(BUF, NS); }

  // ---- pass 0: channels 0-31 (even pk steps)
  STAGE(0)
  __syncthreads();
  STEPP(0,  bb0, 6)  STEPP(2,  bb1, 8)  STEPP(4,  bb2, 10)
  STEPP(6,  bb0, 12) STEPP(8,  bb1, 14) STEPP(10, bb2, 16)
  STEPP(12, bb0, 1)  STEPP(14, bb1, 3)  STEPP(16, bb2, 5)
  __syncthreads();
  // ---- pass 1: channels 32-63 (odd pk steps)
  STAGE(1)
  __syncthreads();
  STEPP(1,  bb0, 7)  STEPP(3,  bb1, 9)  STEPP(5,  bb2, 11)
  STEPP(7,  bb0, 13) STEPP(9,  bb1, 15) STEPP(11, bb2, 17)
  STEPP(13, bb0, -1) STEPP(15, bb1, -1) STEPP(17, bb2, -1)

  // ---- epilogue: att = sigmoid((sum_oc attn_w[oc]*relu(z+bias2[oc]) + b)*mask)
  float aw[4], bz[4];
  #pragma unroll
  for(int j = 0; j < 4; ++j){ aw[j] = attnw[(j << 4) + lm]; bz[j] = bias2[(j << 4) + lm]; }
  const float dir = dirv[b];
  const float jf = (float)(h0 + wv) * (1.f / 256.f);
  const float maskv = (dir > 0.5f) ? (0.5f + 0.5f * jf) : (1.f - 0.5f * jf);
  const float ab = attnb[0];
  #pragma unroll
  for(int i = 0; i < 4; ++i){
    #pragma unroll
    for(int r = 0; r < 4; ++r){
      float lsum = 0.f;
      #pragma unroll
      for(int j = 0; j < 4; ++j)
        lsum = fmaf(aw[j], fmaxf(acc[i][j][r] + bz[j], 0.f), lsum);
      lsum += __shfl_xor(lsum, 8);
      lsum += __shfl_xor(lsum, 4);
      lsum += __shfl_xor(lsum, 2);
      lsum += __shfl_xor(lsum, 1);
      if(lm == (i << 2) + r){
        float sg = 1.f / (1.f + __expf(-(lsum + ab) * maskv));
        att_s[(wv << 6) + (i << 4) + (lg << 2) + r] = sg;
      }
    }
  }
  __syncthreads();

  // ---- output: out = x * att  (x re-read fp32 from global, f4v both ways)
  const int wq = t & 15, cb = t >> 4;
  #pragma unroll
  for(int k = 0; k < 16; ++k){
    const int ch  = cb + ((k & 3) << 4);
    const int row = k >> 2;
    const size_t off = bbase + (size_t)ch * PLANE + (size_t)(h0 + row) * XW
                     + w0 + (wq << 2);
    f4v xv = *(const f4v*)(x + off);
    f4v av = *(const f4v*)(att_s + (row << 6) + (wq << 2));
    f4v o;
    o[0] = xv[0] * av[0]; o[1] = xv[1] * av[1];
    o[2] = xv[2] * av[2]; o[3] = xv[3] * av[3];
    *(f4v*)(out + off) = o;
  }
#undef ALOAD
#undef BLOAD
#undef MF
#undef STEPP
#undef STAGE
}

extern "C" void kernel_launch(void* const* d_in, const int* in_sizes, int n_in,
                              void* d_out, int out_size, void* d_ws, size_t ws_size,
                              hipStream_t stream){
  const float* x     = (const float*)d_in[0];
  const float* convw = (const float*)d_in[1];
  const float* convb = (const float*)d_in[2];
  const float* gamma = (const float*)d_in[3];
  const float* beta  = (const float*)d_in[4];
  const float* mean  = (const float*)d_in[5];
  const float* var   = (const float*)d_in[6];
  const float* attnw = (const float*)d_in[7];
  const float* attnb = (const float*)d_in[8];
  const float* d1w   = (const float*)d_in[9];
  const float* d1b   = (const float*)d_in[10];
  const float* d2w   = (const float*)d_in[11];
  const float* d2b   = (const float*)d_in[12];
  float* out = (float*)d_out;
  char*  ws  = (char*)d_ws;
  // ws: pooled @0 (4KB) | dirv @4096 | bias2 @4352 | pk @5120 (73728B)
  float* pooled = (float*)ws;
  float* dirv   = (float*)(ws + 4096);
  float* bias2  = (float*)(ws + 4352);
  unsigned short* pk = (unsigned short*)(ws + 5120);
  float* outdir = out + (size_t)16 * 64 * 256 * 256;

  pool_k<<<1024, 256, 0, stream>>>(x, pooled);
  prep_k<<<145, 256, 0, stream>>>(convw, convb, gamma, beta, mean, var,
                                  d1w, d1b, d2w, d2b, pooled, dirv, bias2, pk, outdir);
  main_k<<<4096, 256, 0, stream>>>(x, attnw, attnb, dirv, bias2, pk, out);
}